// Round 10
// baseline (433.724 us; speedup 1.0000x reference)
//
#include <hip/hip_runtime.h>
#include <math.h>

#define NN 512
#define CSd 384
#define CATd 2112
#define KF_CHUNK 264
#define KF_SPLIT 8

// ---------------- Kernel 1a: fused projection GEMM ----------------
__global__ void k_projgemm(const float* __restrict__ s,
                           const float* __restrict__ w_q, const float* __restrict__ b_q,
                           const float* __restrict__ w_kv, const float* __restrict__ b_kv,
                           const float* __restrict__ w_qp, const float* __restrict__ b_qp,
                           const float* __restrict__ w_kvp, const float* __restrict__ b_kvp,
                           float* __restrict__ proj)
{
  __shared__ float sT[384 * 40];
  const int t  = threadIdx.x;
  const int i0 = blockIdx.x * 32;
  const int c0 = blockIdx.y * 64;

  for (int u = t; u < 32 * 384; u += 256) {
    int row = u / 384, col = u % 384;
    sT[col * 40 + row] = s[(i0 + row) * CSd + col];
  }
  __syncthreads();

  const int c    = t & 63;
  const int rgrp = t >> 6;
  const int gc   = c0 + c;

  const float* wp;
  int stride;
  float bias;
  if (gc < 192)      { wp = w_q   + gc;         stride = 192; bias = b_q[gc]; }
  else if (gc < 576) { wp = w_kv  + (gc - 192); stride = 384; bias = b_kv[gc - 192]; }
  else if (gc < 720) { wp = w_qp  + (gc - 576); stride = 144; bias = b_qp[gc - 576]; }
  else               { wp = w_kvp + (gc - 720); stride = 432; bias = b_kvp[gc - 720]; }

  float acc[8];
#pragma unroll
  for (int j = 0; j < 8; j++) acc[j] = bias;

  const int r0 = rgrp * 8;
#pragma unroll 4
  for (int kk = 0; kk < 384; kk++) {
    float wv = *wp; wp += stride;
    const float4 a0 = *reinterpret_cast<const float4*>(&sT[kk * 40 + r0]);
    const float4 a1 = *reinterpret_cast<const float4*>(&sT[kk * 40 + r0 + 4]);
    acc[0] += a0.x * wv; acc[1] += a0.y * wv; acc[2] += a0.z * wv; acc[3] += a0.w * wv;
    acc[4] += a1.x * wv; acc[5] += a1.y * wv; acc[6] += a1.z * wv; acc[7] += a1.w * wv;
  }
#pragma unroll
  for (int j = 0; j < 8; j++)
    proj[(size_t)(i0 + r0 + j) * 1152 + gc] = acc[j];
}

// ---------------- Kernel 1b: scatter q/kT/vcatT + rotate points ----------------
__global__ void k_rot(const float* __restrict__ proj,
                      const float* __restrict__ rot, const float* __restrict__ trans,
                      float* __restrict__ q, float* __restrict__ kT, float* __restrict__ vcatT,
                      float* __restrict__ qp, float* __restrict__ kpT)
{
  __shared__ float ptsL[576];
  const int i = blockIdx.x, t = threadIdx.x;
  const float* pr = proj + (size_t)i * 1152;

  for (int u = t; u < 576; u += 256) ptsL[u] = pr[576 + u];

  for (int cI = t; cI < 576; cI += 256) {
    float pv = pr[cI];
    if (cI < 192) q[i * 192 + cI] = pv;
    else {
      int local = cI - 192, h = local >> 5, cc = local & 31;
      if (cc < 16) kT[(size_t)(h * 16 + cc) * NN + i] = pv;
      else         vcatT[(size_t)(h * 16 + (cc - 16)) * NN + i] = pv;
    }
  }
  __syncthreads();

  for (int p = t; p < 192; p += 256) {
    float x, y, zz;
    if (p < 48) { x = ptsL[p]; y = ptsL[48 + p]; zz = ptsL[96 + p]; }
    else { int idx = p - 48; x = ptsL[144 + idx]; y = ptsL[288 + idx]; zz = ptsL[432 + idx]; }
    const float* Rm = rot + i * 9;
    const float* tr = trans + i * 3;
    float rx = Rm[0] * x + Rm[1] * y + Rm[2] * zz + tr[0];
    float ry = Rm[3] * x + Rm[4] * y + Rm[5] * zz + tr[1];
    float rz = Rm[6] * x + Rm[7] * y + Rm[8] * zz + tr[2];
    if (p < 48) {
      float* d = qp + ((size_t)i * 48 + p) * 3;
      d[0] = rx; d[1] = ry; d[2] = rz;
    } else {
      int idx = p - 48, h = idx / 12, pp = idx % 12;
      if (pp < 4) {
        size_t rbase = (size_t)((h * 4 + pp) * 3) * NN + i;
        kpT[rbase] = rx; kpT[rbase + NN] = ry; kpT[rbase + 2 * NN] = rz;
      } else {
        size_t rbase = (size_t)(192 + (h * 8 + pp - 4) * 3) * NN + i;
        vcatT[rbase] = rx; vcatT[rbase + NN] = ry; vcatT[rbase + 2 * NN] = rz;
      }
    }
  }
}

// ---------------- Kernel 2: logits (c-split + h-split, max occupancy) ----------------
// grid (512 i, 4 jq), 256 threads: thread = (jl = t&127, ch = t>>7)
__global__ void __launch_bounds__(256, 8)
k_logits(const float* __restrict__ z, const float* __restrict__ w_b,
         const float* __restrict__ b_b, const float* __restrict__ mask,
         const float* __restrict__ q, const float* __restrict__ kT,
         const float* __restrict__ qp, const float* __restrict__ kpT,
         const float* __restrict__ hws,
         float* __restrict__ a)
{
  __shared__ float red[128][2][13];
  __shared__ float hwL[12];
  const int t  = threadIdx.x;
  const int i  = blockIdx.x;
  const int jq = blockIdx.y;
  const int jl = t & 127;
  const int j  = jq * 128 + jl;
  const int ch = t >> 7;

  if (t < 12) hwL[t] = 0.13608276348f * log1pf(expf(hws[t]));

  // ---- z @ w_b partial over this thread's 64-c half ----
  float acc[12];
#pragma unroll
  for (int h = 0; h < 12; h++) acc[h] = 0.f;

  const float4* zr = reinterpret_cast<const float4*>(z + ((size_t)i * NN + j) * 128 + ch * 64);
#pragma unroll
  for (int u = 0; u < 16; u++) {
    const float4 zv = zr[u];
    const int c0 = ch * 64 + u * 4;
#pragma unroll
    for (int h = 0; h < 12; h++) {
      acc[h] += zv.x * w_b[(c0 + 0) * 12 + h]
              + zv.y * w_b[(c0 + 1) * 12 + h]
              + zv.z * w_b[(c0 + 2) * 12 + h]
              + zv.w * w_b[(c0 + 3) * 12 + h];
    }
  }
#pragma unroll
  for (int h = 0; h < 12; h++) red[jl][ch][h] = acc[h];
  __syncthreads();

  // ---- this thread finishes 6 heads for its j ----
  const int hb = ch * 6;
  const float mterm = 100000.0f * (mask[i] * mask[j] - 1.0f);
  const float W_L = 0.57735026919f;
  const float W_C = 0.14433756730f;

#pragma unroll
  for (int hh = 0; hh < 6; hh++) {
    const int h = hb + hh;
    float sv = red[jl][0][h] + red[jl][1][h];
    float dot = 0.f;
#pragma unroll
    for (int c = 0; c < 16; c++)
      dot += q[i * 192 + h * 16 + c] * kT[(size_t)(h * 16 + c) * NN + j];
    float d2 = 0.f;
#pragma unroll
    for (int pc = 0; pc < 12; pc++) {
      float dd = qp[(size_t)i * 144 + h * 12 + pc] - kpT[(size_t)(h * 12 + pc) * NN + j];
      d2 += dd * dd;
    }
    a[((size_t)h * NN + i) * NN + j] =
        W_L * (sv + b_b[h]) + mterm + W_C * dot - 0.5f * hwL[h] * d2;
  }
}

// ---------------- Kernel 3: softmax (P back to a) + o/o_pt + rot/norm ----------------
__global__ void __launch_bounds__(512)
k_pvt(float* __restrict__ a, const float* __restrict__ vcatT,
      const float* __restrict__ rot, const float* __restrict__ trans,
      float* __restrict__ cat)
{
  __shared__ float PL[12 * 516];
  __shared__ float optF[288];
  const int i = blockIdx.x, t = threadIdx.x;
  const int w = t >> 6, l = t & 63;

  for (int u = t; u < 12 * 128; u += 512) {
    int h = u >> 7, c4 = u & 127;
    *reinterpret_cast<float4*>(&PL[h * 516 + c4 * 4]) =
      *reinterpret_cast<const float4*>(&a[((size_t)h * NN + i) * NN + c4 * 4]);
  }
  __syncthreads();

  for (int h = w; h < 12; h += 8) {
    float x[8];
    float m = -1e30f;
#pragma unroll
    for (int k = 0; k < 8; k++) { x[k] = PL[h * 516 + k * 64 + l]; m = fmaxf(m, x[k]); }
    for (int o = 1; o < 64; o <<= 1) m = fmaxf(m, __shfl_xor(m, o));
    float sm = 0.f;
#pragma unroll
    for (int k = 0; k < 8; k++) { x[k] = expf(x[k] - m); sm += x[k]; }
    for (int o = 1; o < 64; o <<= 1) sm += __shfl_xor(sm, o);
    float inv = 1.0f / sm;
#pragma unroll
    for (int k = 0; k < 8; k++) PL[h * 516 + k * 64 + l] = x[k] * inv;
  }
  __syncthreads();

  for (int u = t; u < 12 * 128; u += 512) {
    int h = u >> 7, c4 = u & 127;
    *reinterpret_cast<float4*>(&a[((size_t)h * NN + i) * NN + c4 * 4]) =
      *reinterpret_cast<const float4*>(&PL[h * 516 + c4 * 4]);
  }

  for (int v = w; v < 480; v += 8) {
    const int h = (v < 192) ? (v >> 4) : ((v - 192) / 24);
    const float* vr = vcatT + (size_t)v * NN;
    const float* pr = PL + h * 516;
    float acc = 0.f;
#pragma unroll
    for (int k = 0; k < 8; k++)
      acc += pr[k * 64 + l] * vr[k * 64 + l];
    for (int o = 1; o < 64; o <<= 1) acc += __shfl_xor(acc, o);
    if (l == 0) {
      if (v < 192) cat[(size_t)i * CATd + v] = acc;
      else         optF[v - 192] = acc;
    }
  }
  __syncthreads();

  if (t < 96) {
    const int h = t >> 3, p = t & 7;
    const float* Rm = rot + i * 9;
    const float* tr = trans + i * 3;
    float ox = optF[(h * 8 + p) * 3 + 0] - tr[0];
    float oy = optF[(h * 8 + p) * 3 + 1] - tr[1];
    float oz = optF[(h * 8 + p) * 3 + 2] - tr[2];
    float rx = Rm[0] * ox + Rm[3] * oy + Rm[6] * oz;
    float ry = Rm[1] * ox + Rm[4] * oy + Rm[7] * oz;
    float rz = Rm[2] * ox + Rm[5] * oy + Rm[8] * oz;
    float nrm = sqrtf(rx * rx + ry * ry + rz * rz + 1e-8f);
    size_t b = (size_t)i * CATd;
    cat[b + 192 + t] = rx; cat[b + 288 + t] = ry;
    cat[b + 384 + t] = rz; cat[b + 480 + t] = nrm;
  }
}

// ---------------- Kernel 4: o_pair partials, z streamed coalesced ----------------
__global__ void k_opair(const float* __restrict__ a, const float* __restrict__ z,
                        float* __restrict__ opart)
{
  __shared__ float PL[12 * 128];
  __shared__ float red[4][64][26];
  const int jb = blockIdx.x, i = blockIdx.y;
  const int t = threadIdx.x, c2 = t & 63, jq = t >> 6;

  for (int u = t; u < 384; u += 256) {
    int h = u >> 5, c4 = u & 31;
    *reinterpret_cast<float4*>(&PL[h * 128 + c4 * 4]) =
      *reinterpret_cast<const float4*>(&a[((size_t)h * NN + i) * NN + jb * 128 + c4 * 4]);
  }
  __syncthreads();

  float acc[12][2];
#pragma unroll
  for (int h = 0; h < 12; h++) { acc[h][0] = 0.f; acc[h][1] = 0.f; }

  const int j0 = jb * 128 + jq * 32;
  const float2* zr = reinterpret_cast<const float2*>(z + ((size_t)i * NN + j0) * 128) + c2;
  for (int jj = 0; jj < 32; jj++) {
    float2 zv = zr[(size_t)jj * 64];
#pragma unroll
    for (int h = 0; h < 12; h++) {
      float pv = PL[h * 128 + jq * 32 + jj];
      acc[h][0] += pv * zv.x; acc[h][1] += pv * zv.y;
    }
  }

#pragma unroll
  for (int h = 0; h < 12; h++) {
    red[jq][c2][h * 2]     = acc[h][0];
    red[jq][c2][h * 2 + 1] = acc[h][1];
  }
  __syncthreads();

  for (int e = t; e < 1536; e += 256) {
    int h = e >> 7, c = e & 127;
    int ci = c >> 1, half = c & 1;
    float sv = red[0][ci][h * 2 + half] + red[1][ci][h * 2 + half]
             + red[2][ci][h * 2 + half] + red[3][ci][h * 2 + half];
    opart[((size_t)i * 4 + jb) * 1536 + e] = sv;
  }
}

// ---------------- Kernel 5: reduce o_pair partials into cat ----------------
__global__ void k_opreduce(const float* __restrict__ opart, float* __restrict__ cat)
{
  const int idx = blockIdx.x * 256 + threadIdx.x;
  const int i = idx / 1536, e = idx - i * 1536;
  const float* pb = opart + (size_t)i * 4 * 1536 + e;
  cat[(size_t)i * CATd + 576 + e] = pb[0] + pb[1536] + pb[3072] + pb[4608];
}

// ---------------- Kernel 6: split-K GEMM out = cat @ w_out ----------------
__global__ void k_final(const float* __restrict__ cat, const float* __restrict__ w_out,
                        float* __restrict__ part)
{
  __shared__ float sT[KF_CHUNK * 36];
  const int t  = threadIdx.x;
  const int i0 = blockIdx.x * 32;
  const int c0 = blockIdx.y * 64;
  const int k0 = blockIdx.z * KF_CHUNK;

  for (int u = t; u < 32 * KF_CHUNK; u += 256) {
    int row = u / KF_CHUNK, kk = u % KF_CHUNK;
    sT[kk * 36 + row] = cat[(size_t)(i0 + row) * CATd + k0 + kk];
  }
  __syncthreads();

  const int c    = t & 63;
  const int rgrp = t >> 6;
  const int r0   = rgrp * 8;
  const int gc   = c0 + c;

  float acc[8];
#pragma unroll
  for (int j = 0; j < 8; j++) acc[j] = 0.f;

  const float* wp = w_out + (size_t)k0 * 384 + gc;
#pragma unroll 4
  for (int kk = 0; kk < KF_CHUNK; kk++) {
    float wv = wp[(size_t)kk * 384];
    const float4 a0 = *reinterpret_cast<const float4*>(&sT[kk * 36 + r0]);
    const float4 a1 = *reinterpret_cast<const float4*>(&sT[kk * 36 + r0 + 4]);
    acc[0] += a0.x * wv; acc[1] += a0.y * wv; acc[2] += a0.z * wv; acc[3] += a0.w * wv;
    acc[4] += a1.x * wv; acc[5] += a1.y * wv; acc[6] += a1.z * wv; acc[7] += a1.w * wv;
  }

  float* pb = part + (size_t)blockIdx.z * NN * 384;
#pragma unroll
  for (int j = 0; j < 8; j++)
    pb[(size_t)(i0 + r0 + j) * 384 + gc] = acc[j];
}

// ---------------- Kernel 7: reduce partials + bias ----------------
__global__ void k_reduce(const float* __restrict__ part, const float* __restrict__ b_out,
                         float* __restrict__ out)
{
  const int idx = blockIdx.x * 256 + threadIdx.x;
  const int c = idx % 384;
  float acc = b_out[c];
#pragma unroll
  for (int ks = 0; ks < KF_SPLIT; ks++)
    acc += part[(size_t)ks * NN * 384 + idx];
  out[idx] = acc;
}

extern "C" void kernel_launch(void* const* d_in, const int* in_sizes, int n_in,
                              void* d_out, int out_size, void* d_ws, size_t ws_size,
                              hipStream_t stream) {
  const float* s      = (const float*)d_in[0];
  const float* z      = (const float*)d_in[1];
  const float* rot    = (const float*)d_in[2];
  const float* trans  = (const float*)d_in[3];
  const float* mask   = (const float*)d_in[4];
  const float* w_q    = (const float*)d_in[5];
  const float* b_q    = (const float*)d_in[6];
  const float* w_kv   = (const float*)d_in[7];
  const float* b_kv   = (const float*)d_in[8];
  const float* w_qp   = (const float*)d_in[9];
  const float* b_qp   = (const float*)d_in[10];
  const float* w_kvp  = (const float*)d_in[11];
  const float* b_kvp  = (const float*)d_in[12];
  const float* w_b    = (const float*)d_in[13];
  const float* b_b    = (const float*)d_in[14];
  const float* hws    = (const float*)d_in[15];
  const float* w_out  = (const float*)d_in[16];
  const float* b_out  = (const float*)d_in[17];
  float* out = (float*)d_out;

  float* ws    = (float*)d_ws;
  float* q     = ws;                   // 512*192
  float* kT    = q     + 98304;        // [192][512]
  float* vcatT = kT    + 98304;        // [480][512] j-major
  float* qp    = vcatT + 245760;       // 512*144
  float* kpT   = qp    + 73728;        // [144][512]
  float* a     = kpT   + 73728;        // 12*512*512 logits -> P
  float* cat   = a     + 3145728;      // 512*2112
  float* opart = cat   + 1081344;      // 512*4*1536
  float* proj  = a;                    // alias: consumed before k_logits writes a
  float* part  = a;                    // alias: P dead after k_opair

  k_projgemm<<<dim3(16, 18), 256, 0, stream>>>(s, w_q, b_q, w_kv, b_kv,
                                               w_qp, b_qp, w_kvp, b_kvp, proj);
  k_rot<<<512, 256, 0, stream>>>(proj, rot, trans, q, kT, vcatT, qp, kpT);
  k_logits<<<dim3(512, 4), 256, 0, stream>>>(z, w_b, b_b, mask, q, kT, qp, kpT, hws, a);
  k_pvt<<<512, 512, 0, stream>>>(a, vcatT, rot, trans, cat);
  k_opair<<<dim3(4, 512), 256, 0, stream>>>(a, z, opart);
  k_opreduce<<<3072, 256, 0, stream>>>(opart, cat);
  k_final<<<dim3(16, 6, KF_SPLIT), 256, 0, stream>>>(cat, w_out, part);
  k_reduce<<<768, 256, 0, stream>>>(part, b_out, out);
}

// Round 11
// 241.718 us; speedup vs baseline: 1.7943x; 1.7943x over previous
//
#include <hip/hip_runtime.h>
#include <math.h>

#define NN 512
#define CSd 384
#define CATd 2112
#define KF_CHUNK 264
#define KF_SPLIT 8

// ---------------- Kernel 1a: fused projection GEMM ----------------
__global__ void k_projgemm(const float* __restrict__ s,
                           const float* __restrict__ w_q, const float* __restrict__ b_q,
                           const float* __restrict__ w_kv, const float* __restrict__ b_kv,
                           const float* __restrict__ w_qp, const float* __restrict__ b_qp,
                           const float* __restrict__ w_kvp, const float* __restrict__ b_kvp,
                           float* __restrict__ proj)
{
  __shared__ float sT[384 * 40];
  const int t  = threadIdx.x;
  const int i0 = blockIdx.x * 32;
  const int c0 = blockIdx.y * 64;

  for (int u = t; u < 32 * 384; u += 256) {
    int row = u / 384, col = u % 384;
    sT[col * 40 + row] = s[(i0 + row) * CSd + col];
  }
  __syncthreads();

  const int c    = t & 63;
  const int rgrp = t >> 6;
  const int gc   = c0 + c;

  const float* wp;
  int stride;
  float bias;
  if (gc < 192)      { wp = w_q   + gc;         stride = 192; bias = b_q[gc]; }
  else if (gc < 576) { wp = w_kv  + (gc - 192); stride = 384; bias = b_kv[gc - 192]; }
  else if (gc < 720) { wp = w_qp  + (gc - 576); stride = 144; bias = b_qp[gc - 576]; }
  else               { wp = w_kvp + (gc - 720); stride = 432; bias = b_kvp[gc - 720]; }

  float acc[8];
#pragma unroll
  for (int j = 0; j < 8; j++) acc[j] = bias;

  const int r0 = rgrp * 8;
#pragma unroll 4
  for (int kk = 0; kk < 384; kk++) {
    float wv = *wp; wp += stride;
    const float4 a0 = *reinterpret_cast<const float4*>(&sT[kk * 40 + r0]);
    const float4 a1 = *reinterpret_cast<const float4*>(&sT[kk * 40 + r0 + 4]);
    acc[0] += a0.x * wv; acc[1] += a0.y * wv; acc[2] += a0.z * wv; acc[3] += a0.w * wv;
    acc[4] += a1.x * wv; acc[5] += a1.y * wv; acc[6] += a1.z * wv; acc[7] += a1.w * wv;
  }
#pragma unroll
  for (int j = 0; j < 8; j++)
    proj[(size_t)(i0 + r0 + j) * 1152 + gc] = acc[j];
}

// ---------------- Kernel 1b: scatter q/kT/vcatT + rotate points ----------------
__global__ void k_rot(const float* __restrict__ proj,
                      const float* __restrict__ rot, const float* __restrict__ trans,
                      float* __restrict__ q, float* __restrict__ kT, float* __restrict__ vcatT,
                      float* __restrict__ qp, float* __restrict__ kpT)
{
  __shared__ float ptsL[576];
  const int i = blockIdx.x, t = threadIdx.x;
  const float* pr = proj + (size_t)i * 1152;

  for (int u = t; u < 576; u += 256) ptsL[u] = pr[576 + u];

  for (int cI = t; cI < 576; cI += 256) {
    float pv = pr[cI];
    if (cI < 192) q[i * 192 + cI] = pv;
    else {
      int local = cI - 192, h = local >> 5, cc = local & 31;
      if (cc < 16) kT[(size_t)(h * 16 + cc) * NN + i] = pv;
      else         vcatT[(size_t)(h * 16 + (cc - 16)) * NN + i] = pv;
    }
  }
  __syncthreads();

  for (int p = t; p < 192; p += 256) {
    float x, y, zz;
    if (p < 48) { x = ptsL[p]; y = ptsL[48 + p]; zz = ptsL[96 + p]; }
    else { int idx = p - 48; x = ptsL[144 + idx]; y = ptsL[288 + idx]; zz = ptsL[432 + idx]; }
    const float* Rm = rot + i * 9;
    const float* tr = trans + i * 3;
    float rx = Rm[0] * x + Rm[1] * y + Rm[2] * zz + tr[0];
    float ry = Rm[3] * x + Rm[4] * y + Rm[5] * zz + tr[1];
    float rz = Rm[6] * x + Rm[7] * y + Rm[8] * zz + tr[2];
    if (p < 48) {
      float* d = qp + ((size_t)i * 48 + p) * 3;
      d[0] = rx; d[1] = ry; d[2] = rz;
    } else {
      int idx = p - 48, h = idx / 12, pp = idx % 12;
      if (pp < 4) {
        size_t rbase = (size_t)((h * 4 + pp) * 3) * NN + i;
        kpT[rbase] = rx; kpT[rbase + NN] = ry; kpT[rbase + 2 * NN] = rz;
      } else {
        size_t rbase = (size_t)(192 + (h * 8 + pp - 4) * 3) * NN + i;
        vcatT[rbase] = rx; vcatT[rbase + NN] = ry; vcatT[rbase + 2 * NN] = rz;
      }
    }
  }
}

// ---------------- Kernel 2: logits (c-split + h-split; NO min-wave clamp) ----------------
// grid (512 i, 4 jq), 256 threads: thread = (jl = t&127, ch = t>>7)
__global__ void __launch_bounds__(256)
k_logits(const float* __restrict__ z, const float* __restrict__ w_b,
         const float* __restrict__ b_b, const float* __restrict__ mask,
         const float* __restrict__ q, const float* __restrict__ kT,
         const float* __restrict__ qp, const float* __restrict__ kpT,
         const float* __restrict__ hws,
         float* __restrict__ a)
{
  __shared__ float red[128][2][13];
  __shared__ float hwL[12];
  const int t  = threadIdx.x;
  const int i  = blockIdx.x;
  const int jq = blockIdx.y;
  const int jl = t & 127;
  const int j  = jq * 128 + jl;
  const int ch = t >> 7;

  if (t < 12) hwL[t] = 0.13608276348f * log1pf(expf(hws[t]));

  // ---- z @ w_b partial over this thread's 64-c half (batched 4xfloat4) ----
  float acc[12];
#pragma unroll
  for (int h = 0; h < 12; h++) acc[h] = 0.f;

  const float4* zr = reinterpret_cast<const float4*>(z + ((size_t)i * NN + j) * 128 + ch * 64);
#pragma unroll
  for (int b4 = 0; b4 < 4; b4++) {
    float4 zv[4];
#pragma unroll
    for (int u = 0; u < 4; u++) zv[u] = zr[b4 * 4 + u];
#pragma unroll
    for (int u = 0; u < 4; u++) {
      const int c0 = ch * 64 + b4 * 16 + u * 4;
#pragma unroll
      for (int h = 0; h < 12; h++) {
        acc[h] += zv[u].x * w_b[(c0 + 0) * 12 + h]
                + zv[u].y * w_b[(c0 + 1) * 12 + h]
                + zv[u].z * w_b[(c0 + 2) * 12 + h]
                + zv[u].w * w_b[(c0 + 3) * 12 + h];
      }
    }
  }
#pragma unroll
  for (int h = 0; h < 12; h++) red[jl][ch][h] = acc[h];
  __syncthreads();

  // ---- this thread finishes 6 heads for its j ----
  const int hb = ch * 6;
  const float mterm = 100000.0f * (mask[i] * mask[j] - 1.0f);
  const float W_L = 0.57735026919f;
  const float W_C = 0.14433756730f;

#pragma unroll
  for (int hh = 0; hh < 6; hh++) {
    const int h = hb + hh;
    float sv = red[jl][0][h] + red[jl][1][h];
    float dot = 0.f;
#pragma unroll
    for (int c = 0; c < 16; c++)
      dot += q[i * 192 + h * 16 + c] * kT[(size_t)(h * 16 + c) * NN + j];
    float d2 = 0.f;
#pragma unroll
    for (int pc = 0; pc < 12; pc++) {
      float dd = qp[(size_t)i * 144 + h * 12 + pc] - kpT[(size_t)(h * 12 + pc) * NN + j];
      d2 += dd * dd;
    }
    a[((size_t)h * NN + i) * NN + j] =
        W_L * (sv + b_b[h]) + mterm + W_C * dot - 0.5f * hwL[h] * d2;
  }
}

// ---------------- Kernel 3: softmax (P back to a) + o/o_pt + rot/norm ----------------
__global__ void __launch_bounds__(512)
k_pvt(float* __restrict__ a, const float* __restrict__ vcatT,
      const float* __restrict__ rot, const float* __restrict__ trans,
      float* __restrict__ cat)
{
  __shared__ float PL[12 * 516];
  __shared__ float optF[288];
  const int i = blockIdx.x, t = threadIdx.x;
  const int w = t >> 6, l = t & 63;

  for (int u = t; u < 12 * 128; u += 512) {
    int h = u >> 7, c4 = u & 127;
    *reinterpret_cast<float4*>(&PL[h * 516 + c4 * 4]) =
      *reinterpret_cast<const float4*>(&a[((size_t)h * NN + i) * NN + c4 * 4]);
  }
  __syncthreads();

  for (int h = w; h < 12; h += 8) {
    float x[8];
    float m = -1e30f;
#pragma unroll
    for (int k = 0; k < 8; k++) { x[k] = PL[h * 516 + k * 64 + l]; m = fmaxf(m, x[k]); }
    for (int o = 1; o < 64; o <<= 1) m = fmaxf(m, __shfl_xor(m, o));
    float sm = 0.f;
#pragma unroll
    for (int k = 0; k < 8; k++) { x[k] = expf(x[k] - m); sm += x[k]; }
    for (int o = 1; o < 64; o <<= 1) sm += __shfl_xor(sm, o);
    float inv = 1.0f / sm;
#pragma unroll
    for (int k = 0; k < 8; k++) PL[h * 516 + k * 64 + l] = x[k] * inv;
  }
  __syncthreads();

  for (int u = t; u < 12 * 128; u += 512) {
    int h = u >> 7, c4 = u & 127;
    *reinterpret_cast<float4*>(&a[((size_t)h * NN + i) * NN + c4 * 4]) =
      *reinterpret_cast<const float4*>(&PL[h * 516 + c4 * 4]);
  }

  for (int v = w; v < 480; v += 8) {
    const int h = (v < 192) ? (v >> 4) : ((v - 192) / 24);
    const float* vr = vcatT + (size_t)v * NN;
    const float* pr = PL + h * 516;
    float acc = 0.f;
#pragma unroll
    for (int k = 0; k < 8; k++)
      acc += pr[k * 64 + l] * vr[k * 64 + l];
    for (int o = 1; o < 64; o <<= 1) acc += __shfl_xor(acc, o);
    if (l == 0) {
      if (v < 192) cat[(size_t)i * CATd + v] = acc;
      else         optF[v - 192] = acc;
    }
  }
  __syncthreads();

  if (t < 96) {
    const int h = t >> 3, p = t & 7;
    const float* Rm = rot + i * 9;
    const float* tr = trans + i * 3;
    float ox = optF[(h * 8 + p) * 3 + 0] - tr[0];
    float oy = optF[(h * 8 + p) * 3 + 1] - tr[1];
    float oz = optF[(h * 8 + p) * 3 + 2] - tr[2];
    float rx = Rm[0] * ox + Rm[3] * oy + Rm[6] * oz;
    float ry = Rm[1] * ox + Rm[4] * oy + Rm[7] * oz;
    float rz = Rm[2] * ox + Rm[5] * oy + Rm[8] * oz;
    float nrm = sqrtf(rx * rx + ry * ry + rz * rz + 1e-8f);
    size_t b = (size_t)i * CATd;
    cat[b + 192 + t] = rx; cat[b + 288 + t] = ry;
    cat[b + 384 + t] = rz; cat[b + 480 + t] = nrm;
  }
}

// ---------------- Kernel 4: o_pair partials, z streamed coalesced ----------------
__global__ void k_opair(const float* __restrict__ a, const float* __restrict__ z,
                        float* __restrict__ opart)
{
  __shared__ float PL[12 * 128];
  __shared__ float red[4][64][26];
  const int jb = blockIdx.x, i = blockIdx.y;
  const int t = threadIdx.x, c2 = t & 63, jq = t >> 6;

  for (int u = t; u < 384; u += 256) {
    int h = u >> 5, c4 = u & 31;
    *reinterpret_cast<float4*>(&PL[h * 128 + c4 * 4]) =
      *reinterpret_cast<const float4*>(&a[((size_t)h * NN + i) * NN + jb * 128 + c4 * 4]);
  }
  __syncthreads();

  float acc[12][2];
#pragma unroll
  for (int h = 0; h < 12; h++) { acc[h][0] = 0.f; acc[h][1] = 0.f; }

  const int j0 = jb * 128 + jq * 32;
  const float2* zr = reinterpret_cast<const float2*>(z + ((size_t)i * NN + j0) * 128) + c2;
  for (int jj = 0; jj < 32; jj++) {
    float2 zv = zr[(size_t)jj * 64];
#pragma unroll
    for (int h = 0; h < 12; h++) {
      float pv = PL[h * 128 + jq * 32 + jj];
      acc[h][0] += pv * zv.x; acc[h][1] += pv * zv.y;
    }
  }

#pragma unroll
  for (int h = 0; h < 12; h++) {
    red[jq][c2][h * 2]     = acc[h][0];
    red[jq][c2][h * 2 + 1] = acc[h][1];
  }
  __syncthreads();

  for (int e = t; e < 1536; e += 256) {
    int h = e >> 7, c = e & 127;
    int ci = c >> 1, half = c & 1;
    float sv = red[0][ci][h * 2 + half] + red[1][ci][h * 2 + half]
             + red[2][ci][h * 2 + half] + red[3][ci][h * 2 + half];
    opart[((size_t)i * 4 + jb) * 1536 + e] = sv;
  }
}

// ---------------- Kernel 5: reduce o_pair partials into cat ----------------
__global__ void k_opreduce(const float* __restrict__ opart, float* __restrict__ cat)
{
  const int idx = blockIdx.x * 256 + threadIdx.x;
  const int i = idx / 1536, e = idx - i * 1536;
  const float* pb = opart + (size_t)i * 4 * 1536 + e;
  cat[(size_t)i * CATd + 576 + e] = pb[0] + pb[1536] + pb[3072] + pb[4608];
}

// ---------------- Kernel 6: split-K GEMM out = cat @ w_out ----------------
__global__ void k_final(const float* __restrict__ cat, const float* __restrict__ w_out,
                        float* __restrict__ part)
{
  __shared__ float sT[KF_CHUNK * 36];
  const int t  = threadIdx.x;
  const int i0 = blockIdx.x * 32;
  const int c0 = blockIdx.y * 64;
  const int k0 = blockIdx.z * KF_CHUNK;

  for (int u = t; u < 32 * KF_CHUNK; u += 256) {
    int row = u / KF_CHUNK, kk = u % KF_CHUNK;
    sT[kk * 36 + row] = cat[(size_t)(i0 + row) * CATd + k0 + kk];
  }
  __syncthreads();

  const int c    = t & 63;
  const int rgrp = t >> 6;
  const int r0   = rgrp * 8;
  const int gc   = c0 + c;

  float acc[8];
#pragma unroll
  for (int j = 0; j < 8; j++) acc[j] = 0.f;

  const float* wp = w_out + (size_t)k0 * 384 + gc;
#pragma unroll 4
  for (int kk = 0; kk < KF_CHUNK; kk++) {
    float wv = wp[(size_t)kk * 384];
    const float4 a0 = *reinterpret_cast<const float4*>(&sT[kk * 36 + r0]);
    const float4 a1 = *reinterpret_cast<const float4*>(&sT[kk * 36 + r0 + 4]);
    acc[0] += a0.x * wv; acc[1] += a0.y * wv; acc[2] += a0.z * wv; acc[3] += a0.w * wv;
    acc[4] += a1.x * wv; acc[5] += a1.y * wv; acc[6] += a1.z * wv; acc[7] += a1.w * wv;
  }

  float* pb = part + (size_t)blockIdx.z * NN * 384;
#pragma unroll
  for (int j = 0; j < 8; j++)
    pb[(size_t)(i0 + r0 + j) * 384 + gc] = acc[j];
}

// ---------------- Kernel 7: reduce partials + bias ----------------
__global__ void k_reduce(const float* __restrict__ part, const float* __restrict__ b_out,
                         float* __restrict__ out)
{
  const int idx = blockIdx.x * 256 + threadIdx.x;
  const int c = idx % 384;
  float acc = b_out[c];
#pragma unroll
  for (int ks = 0; ks < KF_SPLIT; ks++)
    acc += part[(size_t)ks * NN * 384 + idx];
  out[idx] = acc;
}

extern "C" void kernel_launch(void* const* d_in, const int* in_sizes, int n_in,
                              void* d_out, int out_size, void* d_ws, size_t ws_size,
                              hipStream_t stream) {
  const float* s      = (const float*)d_in[0];
  const float* z      = (const float*)d_in[1];
  const float* rot    = (const float*)d_in[2];
  const float* trans  = (const float*)d_in[3];
  const float* mask   = (const float*)d_in[4];
  const float* w_q    = (const float*)d_in[5];
  const float* b_q    = (const float*)d_in[6];
  const float* w_kv   = (const float*)d_in[7];
  const float* b_kv   = (const float*)d_in[8];
  const float* w_qp   = (const float*)d_in[9];
  const float* b_qp   = (const float*)d_in[10];
  const float* w_kvp  = (const float*)d_in[11];
  const float* b_kvp  = (const float*)d_in[12];
  const float* w_b    = (const float*)d_in[13];
  const float* b_b    = (const float*)d_in[14];
  const float* hws    = (const float*)d_in[15];
  const float* w_out  = (const float*)d_in[16];
  const float* b_out  = (const float*)d_in[17];
  float* out = (float*)d_out;

  float* ws    = (float*)d_ws;
  float* q     = ws;                   // 512*192
  float* kT    = q     + 98304;        // [192][512]
  float* vcatT = kT    + 98304;        // [480][512] j-major
  float* qp    = vcatT + 245760;       // 512*144
  float* kpT   = qp    + 73728;        // [144][512]
  float* a     = kpT   + 73728;        // 12*512*512 logits -> P
  float* cat   = a     + 3145728;      // 512*2112
  float* opart = cat   + 1081344;      // 512*4*1536
  float* proj  = a;                    // alias: consumed before k_logits writes a
  float* part  = a;                    // alias: P dead after k_opair

  k_projgemm<<<dim3(16, 18), 256, 0, stream>>>(s, w_q, b_q, w_kv, b_kv,
                                               w_qp, b_qp, w_kvp, b_kvp, proj);
  k_rot<<<512, 256, 0, stream>>>(proj, rot, trans, q, kT, vcatT, qp, kpT);
  k_logits<<<dim3(512, 4), 256, 0, stream>>>(z, w_b, b_b, mask, q, kT, qp, kpT, hws, a);
  k_pvt<<<512, 512, 0, stream>>>(a, vcatT, rot, trans, cat);
  k_opair<<<dim3(4, 512), 256, 0, stream>>>(a, z, opart);
  k_opreduce<<<3072, 256, 0, stream>>>(opart, cat);
  k_final<<<dim3(16, 6, KF_SPLIT), 256, 0, stream>>>(cat, w_out, part);
  k_reduce<<<768, 256, 0, stream>>>(part, b_out, out);
}

// Round 12
// 210.943 us; speedup vs baseline: 2.0561x; 1.1459x over previous
//
#include <hip/hip_runtime.h>
#include <math.h>

#define NN 512
#define CSd 384
#define CATd 2112
#define KF_CHUNK 264
#define KF_SPLIT 8

// ---------------- Kernel 1a: fused projection GEMM ----------------
__global__ void k_projgemm(const float* __restrict__ s,
                           const float* __restrict__ w_q, const float* __restrict__ b_q,
                           const float* __restrict__ w_kv, const float* __restrict__ b_kv,
                           const float* __restrict__ w_qp, const float* __restrict__ b_qp,
                           const float* __restrict__ w_kvp, const float* __restrict__ b_kvp,
                           float* __restrict__ proj)
{
  __shared__ float sT[384 * 40];
  const int t  = threadIdx.x;
  const int i0 = blockIdx.x * 32;
  const int c0 = blockIdx.y * 64;

  for (int u = t; u < 32 * 384; u += 256) {
    int row = u / 384, col = u % 384;
    sT[col * 40 + row] = s[(i0 + row) * CSd + col];
  }
  __syncthreads();

  const int c    = t & 63;
  const int rgrp = t >> 6;
  const int gc   = c0 + c;

  const float* wp;
  int stride;
  float bias;
  if (gc < 192)      { wp = w_q   + gc;         stride = 192; bias = b_q[gc]; }
  else if (gc < 576) { wp = w_kv  + (gc - 192); stride = 384; bias = b_kv[gc - 192]; }
  else if (gc < 720) { wp = w_qp  + (gc - 576); stride = 144; bias = b_qp[gc - 576]; }
  else               { wp = w_kvp + (gc - 720); stride = 432; bias = b_kvp[gc - 720]; }

  float acc[8];
#pragma unroll
  for (int j = 0; j < 8; j++) acc[j] = bias;

  const int r0 = rgrp * 8;
#pragma unroll 4
  for (int kk = 0; kk < 384; kk++) {
    float wv = *wp; wp += stride;
    const float4 a0 = *reinterpret_cast<const float4*>(&sT[kk * 40 + r0]);
    const float4 a1 = *reinterpret_cast<const float4*>(&sT[kk * 40 + r0 + 4]);
    acc[0] += a0.x * wv; acc[1] += a0.y * wv; acc[2] += a0.z * wv; acc[3] += a0.w * wv;
    acc[4] += a1.x * wv; acc[5] += a1.y * wv; acc[6] += a1.z * wv; acc[7] += a1.w * wv;
  }
#pragma unroll
  for (int j = 0; j < 8; j++)
    proj[(size_t)(i0 + r0 + j) * 1152 + gc] = acc[j];
}

// ---------------- Kernel 1b: scatter q/kT/vcatT + rotate points ----------------
__global__ void k_rot(const float* __restrict__ proj,
                      const float* __restrict__ rot, const float* __restrict__ trans,
                      float* __restrict__ q, float* __restrict__ kT, float* __restrict__ vcatT,
                      float* __restrict__ qp, float* __restrict__ kpT)
{
  __shared__ float ptsL[576];
  const int i = blockIdx.x, t = threadIdx.x;
  const float* pr = proj + (size_t)i * 1152;

  for (int u = t; u < 576; u += 256) ptsL[u] = pr[576 + u];

  for (int cI = t; cI < 576; cI += 256) {
    float pv = pr[cI];
    if (cI < 192) q[i * 192 + cI] = pv;
    else {
      int local = cI - 192, h = local >> 5, cc = local & 31;
      if (cc < 16) kT[(size_t)(h * 16 + cc) * NN + i] = pv;
      else         vcatT[(size_t)(h * 16 + (cc - 16)) * NN + i] = pv;
    }
  }
  __syncthreads();

  for (int p = t; p < 192; p += 256) {
    float x, y, zz;
    if (p < 48) { x = ptsL[p]; y = ptsL[48 + p]; zz = ptsL[96 + p]; }
    else { int idx = p - 48; x = ptsL[144 + idx]; y = ptsL[288 + idx]; zz = ptsL[432 + idx]; }
    const float* Rm = rot + i * 9;
    const float* tr = trans + i * 3;
    float rx = Rm[0] * x + Rm[1] * y + Rm[2] * zz + tr[0];
    float ry = Rm[3] * x + Rm[4] * y + Rm[5] * zz + tr[1];
    float rz = Rm[6] * x + Rm[7] * y + Rm[8] * zz + tr[2];
    if (p < 48) {
      float* d = qp + ((size_t)i * 48 + p) * 3;
      d[0] = rx; d[1] = ry; d[2] = rz;
    } else {
      int idx = p - 48, h = idx / 12, pp = idx % 12;
      if (pp < 4) {
        size_t rbase = (size_t)((h * 4 + pp) * 3) * NN + i;
        kpT[rbase] = rx; kpT[rbase + NN] = ry; kpT[rbase + 2 * NN] = rz;
      } else {
        size_t rbase = (size_t)(192 + (h * 8 + pp - 4) * 3) * NN + i;
        vcatT[rbase] = rx; vcatT[rbase + NN] = ry; vcatT[rbase + 2 * NN] = rz;
      }
    }
  }
}

// ---------------- Kernel 2a: a = W_L*(z@w_b + b_b) + mask (pure z stream) ----------------
// grid 1024 (i = b>>1, j-half = b&1), 256 threads; one thread per (i,j); no LDS.
__global__ void k_zbias(const float* __restrict__ z, const float* __restrict__ w_b,
                        const float* __restrict__ b_b, const float* __restrict__ mask,
                        float* __restrict__ a)
{
  const int t = threadIdx.x;
  const int i = blockIdx.x >> 1;
  const int j = ((blockIdx.x & 1) << 8) + t;

  float acc[12];
#pragma unroll
  for (int h = 0; h < 12; h++) acc[h] = 0.f;

  const float4* zr = reinterpret_cast<const float4*>(z + ((size_t)i * NN + j) * 128);
#pragma unroll
  for (int b4 = 0; b4 < 4; b4++) {
    float4 zv[8];
#pragma unroll
    for (int u = 0; u < 8; u++) zv[u] = zr[b4 * 8 + u];
#pragma unroll
    for (int u = 0; u < 8; u++) {
      const int c0 = b4 * 32 + u * 4;
#pragma unroll
      for (int h = 0; h < 12; h++) {
        acc[h] += zv[u].x * w_b[(c0 + 0) * 12 + h]
                + zv[u].y * w_b[(c0 + 1) * 12 + h]
                + zv[u].z * w_b[(c0 + 2) * 12 + h]
                + zv[u].w * w_b[(c0 + 3) * 12 + h];
      }
    }
  }

  const float mterm = 100000.0f * (mask[i] * mask[j] - 1.0f);
  const float W_L = 0.57735026919f;
#pragma unroll
  for (int h = 0; h < 12; h++)
    a[((size_t)h * NN + i) * NN + j] = W_L * (acc[h] + b_b[h]) + mterm;
}

// ---------------- Kernel 2b: a += W_C*qk - 0.5*hw*d2 (L2-resident operands) ----------------
// grid 1024, 256 threads; one thread per (i,j).
__global__ void k_qkpt(const float* __restrict__ q, const float* __restrict__ kT,
                       const float* __restrict__ qp, const float* __restrict__ kpT,
                       const float* __restrict__ hws, float* __restrict__ a)
{
  __shared__ float hwL[12];
  const int t = threadIdx.x;
  const int i = blockIdx.x >> 1;
  const int j = ((blockIdx.x & 1) << 8) + t;

  if (t < 12) hwL[t] = 0.13608276348f * log1pf(expf(hws[t]));
  __syncthreads();

  const float W_C = 0.14433756730f;
#pragma unroll 4
  for (int h = 0; h < 12; h++) {
    float dot = 0.f;
#pragma unroll
    for (int c = 0; c < 16; c++)
      dot += q[i * 192 + h * 16 + c] * kT[(size_t)(h * 16 + c) * NN + j];
    float d2 = 0.f;
#pragma unroll
    for (int pc = 0; pc < 12; pc++) {
      float dd = qp[(size_t)i * 144 + h * 12 + pc] - kpT[(size_t)(h * 12 + pc) * NN + j];
      d2 += dd * dd;
    }
    const size_t idx = ((size_t)h * NN + i) * NN + j;
    a[idx] += W_C * dot - 0.5f * hwL[h] * d2;
  }
}

// ---------------- Kernel 3: softmax (P back to a) + o/o_pt + rot/norm ----------------
__global__ void __launch_bounds__(512)
k_pvt(float* __restrict__ a, const float* __restrict__ vcatT,
      const float* __restrict__ rot, const float* __restrict__ trans,
      float* __restrict__ cat)
{
  __shared__ float PL[12 * 516];
  __shared__ float optF[288];
  const int i = blockIdx.x, t = threadIdx.x;
  const int w = t >> 6, l = t & 63;

  for (int u = t; u < 12 * 128; u += 512) {
    int h = u >> 7, c4 = u & 127;
    *reinterpret_cast<float4*>(&PL[h * 516 + c4 * 4]) =
      *reinterpret_cast<const float4*>(&a[((size_t)h * NN + i) * NN + c4 * 4]);
  }
  __syncthreads();

  for (int h = w; h < 12; h += 8) {
    float x[8];
    float m = -1e30f;
#pragma unroll
    for (int k = 0; k < 8; k++) { x[k] = PL[h * 516 + k * 64 + l]; m = fmaxf(m, x[k]); }
    for (int o = 1; o < 64; o <<= 1) m = fmaxf(m, __shfl_xor(m, o));
    float sm = 0.f;
#pragma unroll
    for (int k = 0; k < 8; k++) { x[k] = expf(x[k] - m); sm += x[k]; }
    for (int o = 1; o < 64; o <<= 1) sm += __shfl_xor(sm, o);
    float inv = 1.0f / sm;
#pragma unroll
    for (int k = 0; k < 8; k++) PL[h * 516 + k * 64 + l] = x[k] * inv;
  }
  __syncthreads();

  for (int u = t; u < 12 * 128; u += 512) {
    int h = u >> 7, c4 = u & 127;
    *reinterpret_cast<float4*>(&a[((size_t)h * NN + i) * NN + c4 * 4]) =
      *reinterpret_cast<const float4*>(&PL[h * 516 + c4 * 4]);
  }

  for (int v = w; v < 480; v += 8) {
    const int h = (v < 192) ? (v >> 4) : ((v - 192) / 24);
    const float* vr = vcatT + (size_t)v * NN;
    const float* pr = PL + h * 516;
    float acc = 0.f;
#pragma unroll
    for (int k = 0; k < 8; k++)
      acc += pr[k * 64 + l] * vr[k * 64 + l];
    for (int o = 1; o < 64; o <<= 1) acc += __shfl_xor(acc, o);
    if (l == 0) {
      if (v < 192) cat[(size_t)i * CATd + v] = acc;
      else         optF[v - 192] = acc;
    }
  }
  __syncthreads();

  if (t < 96) {
    const int h = t >> 3, p = t & 7;
    const float* Rm = rot + i * 9;
    const float* tr = trans + i * 3;
    float ox = optF[(h * 8 + p) * 3 + 0] - tr[0];
    float oy = optF[(h * 8 + p) * 3 + 1] - tr[1];
    float oz = optF[(h * 8 + p) * 3 + 2] - tr[2];
    float rx = Rm[0] * ox + Rm[3] * oy + Rm[6] * oz;
    float ry = Rm[1] * ox + Rm[4] * oy + Rm[7] * oz;
    float rz = Rm[2] * ox + Rm[5] * oy + Rm[8] * oz;
    float nrm = sqrtf(rx * rx + ry * ry + rz * rz + 1e-8f);
    size_t b = (size_t)i * CATd;
    cat[b + 192 + t] = rx; cat[b + 288 + t] = ry;
    cat[b + 384 + t] = rz; cat[b + 480 + t] = nrm;
  }
}

// ---------------- Kernel 4: o_pair partials, z streamed coalesced ----------------
__global__ void k_opair(const float* __restrict__ a, const float* __restrict__ z,
                        float* __restrict__ opart)
{
  __shared__ float PL[12 * 128];
  __shared__ float red[4][64][26];
  const int jb = blockIdx.x, i = blockIdx.y;
  const int t = threadIdx.x, c2 = t & 63, jq = t >> 6;

  for (int u = t; u < 384; u += 256) {
    int h = u >> 5, c4 = u & 31;
    *reinterpret_cast<float4*>(&PL[h * 128 + c4 * 4]) =
      *reinterpret_cast<const float4*>(&a[((size_t)h * NN + i) * NN + jb * 128 + c4 * 4]);
  }
  __syncthreads();

  float acc[12][2];
#pragma unroll
  for (int h = 0; h < 12; h++) { acc[h][0] = 0.f; acc[h][1] = 0.f; }

  const int j0 = jb * 128 + jq * 32;
  const float2* zr = reinterpret_cast<const float2*>(z + ((size_t)i * NN + j0) * 128) + c2;
  for (int jj = 0; jj < 32; jj++) {
    float2 zv = zr[(size_t)jj * 64];
#pragma unroll
    for (int h = 0; h < 12; h++) {
      float pv = PL[h * 128 + jq * 32 + jj];
      acc[h][0] += pv * zv.x; acc[h][1] += pv * zv.y;
    }
  }

#pragma unroll
  for (int h = 0; h < 12; h++) {
    red[jq][c2][h * 2]     = acc[h][0];
    red[jq][c2][h * 2 + 1] = acc[h][1];
  }
  __syncthreads();

  for (int e = t; e < 1536; e += 256) {
    int h = e >> 7, c = e & 127;
    int ci = c >> 1, half = c & 1;
    float sv = red[0][ci][h * 2 + half] + red[1][ci][h * 2 + half]
             + red[2][ci][h * 2 + half] + red[3][ci][h * 2 + half];
    opart[((size_t)i * 4 + jb) * 1536 + e] = sv;
  }
}

// ---------------- Kernel 5: reduce o_pair partials into cat ----------------
__global__ void k_opreduce(const float* __restrict__ opart, float* __restrict__ cat)
{
  const int idx = blockIdx.x * 256 + threadIdx.x;
  const int i = idx / 1536, e = idx - i * 1536;
  const float* pb = opart + (size_t)i * 4 * 1536 + e;
  cat[(size_t)i * CATd + 576 + e] = pb[0] + pb[1536] + pb[3072] + pb[4608];
}

// ---------------- Kernel 6: split-K GEMM out = cat @ w_out ----------------
__global__ void k_final(const float* __restrict__ cat, const float* __restrict__ w_out,
                        float* __restrict__ part)
{
  __shared__ float sT[KF_CHUNK * 36];
  const int t  = threadIdx.x;
  const int i0 = blockIdx.x * 32;
  const int c0 = blockIdx.y * 64;
  const int k0 = blockIdx.z * KF_CHUNK;

  for (int u = t; u < 32 * KF_CHUNK; u += 256) {
    int row = u / KF_CHUNK, kk = u % KF_CHUNK;
    sT[kk * 36 + row] = cat[(size_t)(i0 + row) * CATd + k0 + kk];
  }
  __syncthreads();

  const int c    = t & 63;
  const int rgrp = t >> 6;
  const int r0   = rgrp * 8;
  const int gc   = c0 + c;

  float acc[8];
#pragma unroll
  for (int j = 0; j < 8; j++) acc[j] = 0.f;

  const float* wp = w_out + (size_t)k0 * 384 + gc;
#pragma unroll 4
  for (int kk = 0; kk < KF_CHUNK; kk++) {
    float wv = wp[(size_t)kk * 384];
    const float4 a0 = *reinterpret_cast<const float4*>(&sT[kk * 36 + r0]);
    const float4 a1 = *reinterpret_cast<const float4*>(&sT[kk * 36 + r0 + 4]);
    acc[0] += a0.x * wv; acc[1] += a0.y * wv; acc[2] += a0.z * wv; acc[3] += a0.w * wv;
    acc[4] += a1.x * wv; acc[5] += a1.y * wv; acc[6] += a1.z * wv; acc[7] += a1.w * wv;
  }

  float* pb = part + (size_t)blockIdx.z * NN * 384;
#pragma unroll
  for (int j = 0; j < 8; j++)
    pb[(size_t)(i0 + r0 + j) * 384 + gc] = acc[j];
}

// ---------------- Kernel 7: reduce partials + bias ----------------
__global__ void k_reduce(const float* __restrict__ part, const float* __restrict__ b_out,
                         float* __restrict__ out)
{
  const int idx = blockIdx.x * 256 + threadIdx.x;
  const int c = idx % 384;
  float acc = b_out[c];
#pragma unroll
  for (int ks = 0; ks < KF_SPLIT; ks++)
    acc += part[(size_t)ks * NN * 384 + idx];
  out[idx] = acc;
}

extern "C" void kernel_launch(void* const* d_in, const int* in_sizes, int n_in,
                              void* d_out, int out_size, void* d_ws, size_t ws_size,
                              hipStream_t stream) {
  const float* s      = (const float*)d_in[0];
  const float* z      = (const float*)d_in[1];
  const float* rot    = (const float*)d_in[2];
  const float* trans  = (const float*)d_in[3];
  const float* mask   = (const float*)d_in[4];
  const float* w_q    = (const float*)d_in[5];
  const float* b_q    = (const float*)d_in[6];
  const float* w_kv   = (const float*)d_in[7];
  const float* b_kv   = (const float*)d_in[8];
  const float* w_qp   = (const float*)d_in[9];
  const float* b_qp   = (const float*)d_in[10];
  const float* w_kvp  = (const float*)d_in[11];
  const float* b_kvp  = (const float*)d_in[12];
  const float* w_b    = (const float*)d_in[13];
  const float* b_b    = (const float*)d_in[14];
  const float* hws    = (const float*)d_in[15];
  const float* w_out  = (const float*)d_in[16];
  const float* b_out  = (const float*)d_in[17];
  float* out = (float*)d_out;

  float* ws    = (float*)d_ws;
  float* q     = ws;                   // 512*192
  float* kT    = q     + 98304;        // [192][512]
  float* vcatT = kT    + 98304;        // [480][512] j-major
  float* qp    = vcatT + 245760;       // 512*144
  float* kpT   = qp    + 73728;        // [144][512]
  float* a     = kpT   + 73728;        // 12*512*512 logits -> P
  float* cat   = a     + 3145728;      // 512*2112
  float* opart = cat   + 1081344;      // 512*4*1536
  float* proj  = a;                    // alias: consumed before k_zbias writes a
  float* part  = a;                    // alias: P dead after k_opair

  k_projgemm<<<dim3(16, 18), 256, 0, stream>>>(s, w_q, b_q, w_kv, b_kv,
                                               w_qp, b_qp, w_kvp, b_kvp, proj);
  k_rot<<<512, 256, 0, stream>>>(proj, rot, trans, q, kT, vcatT, qp, kpT);
  k_zbias<<<1024, 256, 0, stream>>>(z, w_b, b_b, mask, a);
  k_qkpt<<<1024, 256, 0, stream>>>(q, kT, qp, kpT, hws, a);
  k_pvt<<<512, 512, 0, stream>>>(a, vcatT, rot, trans, cat);
  k_opair<<<dim3(4, 512), 256, 0, stream>>>(a, z, opart);
  k_opreduce<<<3072, 256, 0, stream>>>(opart, cat);
  k_final<<<dim3(16, 6, KF_SPLIT), 256, 0, stream>>>(cat, w_out, part);
  k_reduce<<<768, 256, 0, stream>>>(part, b_out, out);
}